// Round 20
// baseline (443.131 us; speedup 1.0000x reference)
//
#include <hip/hip_runtime.h>
#include <hip/hip_bf16.h>

typedef __attribute__((ext_vector_type(4))) int intx4;

#define IN_DIM  4096
#define OUT_DIM 4096
#define MROWS   16384
#define GSIZE   128

template <int N> struct IC { static constexpr int value = N; };

__device__ __forceinline__ int q8(float v, float inv) {
    float q = rintf(v * inv);
    q = fmaxf(-127.f, fminf(127.f, q));
    return (int)q & 0xff;
}

#define GLD16(gsrc, ldst)                                                     \
    __builtin_amdgcn_global_load_lds(                                         \
        (const __attribute__((address_space(1))) unsigned int*)(const void*)(gsrc), \
        (__attribute__((address_space(3))) unsigned int*)(void*)(ldst),       \
        16, 0, 0)

// ------------------------------------------------- convert x -> i8 per-row
__global__ void convert_x_i8(const float* __restrict__ x,
                             signed char* __restrict__ xq,
                             float* __restrict__ sx) {
    int row = blockIdx.x;
    int tid = threadIdx.x;                  // 256 threads, 16 elems each
    const float4* xr = (const float4*)(x + (size_t)row * IN_DIM);
    float v[16];
    float mx = 0.f;
#pragma unroll
    for (int k = 0; k < 4; ++k) {
        float4 f = xr[tid * 4 + k];
        v[4 * k + 0] = f.x; v[4 * k + 1] = f.y;
        v[4 * k + 2] = f.z; v[4 * k + 3] = f.w;
        mx = fmaxf(mx, fmaxf(fmaxf(fabsf(f.x), fabsf(f.y)),
                             fmaxf(fabsf(f.z), fabsf(f.w))));
    }
#pragma unroll
    for (int off = 32; off; off >>= 1) mx = fmaxf(mx, __shfl_xor(mx, off));
    __shared__ float wm[4];
    if ((tid & 63) == 0) wm[tid >> 6] = mx;
    __syncthreads();
    float bmax = fmaxf(fmaxf(wm[0], wm[1]), fmaxf(wm[2], wm[3]));
    float inv = bmax > 0.f ? 127.f / bmax : 0.f;
    if (tid == 0) sx[row] = bmax > 0.f ? bmax / 127.f : 0.f;
    int p[4];
#pragma unroll
    for (int k = 0; k < 4; ++k)
        p[k] = q8(v[4*k], inv) | (q8(v[4*k+1], inv) << 8) |
               (q8(v[4*k+2], inv) << 16) | (q8(v[4*k+3], inv) << 24);
    ((int4*)(xq + (size_t)row * IN_DIM))[tid] = make_int4(p[0], p[1], p[2], p[3]);
}

// --------------------------------------- fused decode + quantize W -> i8
__global__ void decode_quant_w(const int* __restrict__ pw,
                               const float* __restrict__ norms,
                               const float* __restrict__ s1,
                               const float* __restrict__ s2,
                               const float* __restrict__ cent,
                               signed char* __restrict__ wq,
                               float* __restrict__ sw) {
    int o   = blockIdx.x;
    int tid = threadIdx.x;
    int g   = tid >> 3;        // group 0..31
    int k   = tid & 7;         // sub-slot: elems [k*8, k*8+8) and +64
    const int* pr = pw + ((size_t)o * 32 + g) * GSIZE;
    float nrm = norms[o * 32 + g];
    const float inv = 0.08838834764831845f; // 1/sqrt(128)

    float v0[8], v1[8];
    float mx = 0.f;
#pragma unroll
    for (int i = 0; i < 8; ++i) {
        int idx = k * 8 + i;
        float e0 = cent[pr[idx]]      * nrm * s2[idx];
        float e1 = cent[pr[idx + 64]] * nrm * s2[idx + 64];
#pragma unroll
        for (int it = 0; it < 7; ++it) {
            float a = e0, b = e1;
            e0 = a + b;
            e1 = a - b;
        }
        v0[i] = e0 * inv * s1[idx];
        v1[i] = e1 * inv * s1[idx + 64];
        mx = fmaxf(mx, fmaxf(fabsf(v0[i]), fabsf(v1[i])));
    }
#pragma unroll
    for (int off = 32; off; off >>= 1) mx = fmaxf(mx, __shfl_xor(mx, off));
    __shared__ float wm[4];
    if ((tid & 63) == 0) wm[tid >> 6] = mx;
    __syncthreads();
    float bmax = fmaxf(fmaxf(wm[0], wm[1]), fmaxf(wm[2], wm[3]));
    float qinv = bmax > 0.f ? 127.f / bmax : 0.f;
    if (tid == 0) sw[o] = bmax > 0.f ? bmax / 127.f : 0.f;

    int p0 = q8(v0[0],qinv) | (q8(v0[1],qinv)<<8) | (q8(v0[2],qinv)<<16) | (q8(v0[3],qinv)<<24);
    int p1 = q8(v0[4],qinv) | (q8(v0[5],qinv)<<8) | (q8(v0[6],qinv)<<16) | (q8(v0[7],qinv)<<24);
    int p2 = q8(v1[0],qinv) | (q8(v1[1],qinv)<<8) | (q8(v1[2],qinv)<<16) | (q8(v1[3],qinv)<<24);
    int p3 = q8(v1[4],qinv) | (q8(v1[5],qinv)<<8) | (q8(v1[6],qinv)<<16) | (q8(v1[7],qinv)<<24);
    signed char* wr = wq + (size_t)o * IN_DIM + g * GSIZE + k * 8;
    *(int2*)wr        = make_int2(p0, p1);
    *(int2*)(wr + 64) = make_int2(p2, p3);
}

// ---------------------------------------------------------------- GEMM i8
// 4 BLOCKS/CU cross-block overlap (R19 had 2): block = 128x128, 4 waves
// (2x2), wave tile 64x64 (acc 4x4 = 64 regs -- fits the 128-reg/wave cap
// of waves_per_eu=4). BK=128, SINGLE-buffer LDS 32 KiB -> 4 blocks x 32 KB
// = 128 KB <= 160. While one block is in its barrier/wait protocol, three
// co-resident blocks feed the MFMA + DS pipes (m114).
// Byte-level LDS pattern identical to R17/R19's proven 0-conflict geometry
// (128B rows, 8x16B chunks, phys = c ^ (row&7)).
//
// Per K-tile j (32 tiles):
//   LD ks0 (8 reads); lgkm0; MFMA 16 (ks0)
//   LD ks1 (8 reads); lgkm0; BAR   (all waves' reads of tile j done)
//   STG tile j+1 (8 GLD/thread)
//   MFMA 16 (ks1)
//   vmcnt(0); BAR                  (tile j+1 resident + readable)
__global__ __launch_bounds__(256)
__attribute__((amdgpu_waves_per_eu(4, 4)))
void gemm_i8(const signed char* __restrict__ Xq,
             const signed char* __restrict__ Wq,
             const float* __restrict__ sx,
             const float* __restrict__ sw,
             const float* __restrict__ bias,
             float* __restrict__ out) {
    __shared__ signed char As[128][128];   // 16 KiB
    __shared__ signed char Bs[128][128];   // 16 KiB

    // bijective XCD swizzle (4096 blocks % 8 == 0); consecutive ids share mt
    int id = (blockIdx.x & 7) * 512 + (blockIdx.x >> 3);
    int mt = id >> 5, nt = id & 31;        // 128 M-tiles x 32 N-tiles
    int m0 = mt * 128, n0 = nt * 128;

    int tid  = threadIdx.x;
    int lane = tid & 63;
    int wid  = tid >> 6;
    int wm = wid >> 1, wn = wid & 1;       // wave tile: (wm*64, wn*64)

    // staging: thread covers 16B phys chunk cp0 of rows sr0 + 32*i
    int sr0 = tid >> 3;        // 0..31
    int cp0 = tid & 7;         // physical chunk position
    int sg0 = cp0 ^ (sr0 & 7); // global chunk (inverse swizzle; +32k keeps &7)

#define STG_TILE(j) do {                                                      \
    const signed char* _a =                                                   \
        Xq + (size_t)(m0 + sr0) * IN_DIM + (size_t)(j)*128 + sg0*16;          \
    GLD16(_a,                &As[sr0][cp0 * 16]);                             \
    GLD16(_a + 32 * IN_DIM,  &As[sr0 + 32][cp0 * 16]);                        \
    GLD16(_a + 64 * IN_DIM,  &As[sr0 + 64][cp0 * 16]);                        \
    GLD16(_a + 96 * IN_DIM,  &As[sr0 + 96][cp0 * 16]);                        \
    const signed char* _b =                                                   \
        Wq + (size_t)(n0 + sr0) * IN_DIM + (size_t)(j)*128 + sg0*16;          \
    GLD16(_b,                &Bs[sr0][cp0 * 16]);                             \
    GLD16(_b + 32 * IN_DIM,  &Bs[sr0 + 32][cp0 * 16]);                        \
    GLD16(_b + 64 * IN_DIM,  &Bs[sr0 + 64][cp0 * 16]);                        \
    GLD16(_b + 96 * IN_DIM,  &Bs[sr0 + 96][cp0 * 16]);                        \
  } while (0)

    int rl = lane & 15, kc = lane >> 4;
    intx4 a_[4], b_[4];
    intx4 acc[4][4] = {};

#define LD_A(m, ks)                                                           \
    a_[m] = *(const intx4*)&As[wm*64 + (m)*16 + rl]                           \
        [((((ks)*4 + kc) ^ (rl & 7)) << 4)]
#define LD_B(n, ks)                                                           \
    b_[n] = *(const intx4*)&Bs[wn*64 + (n)*16 + rl]                           \
        [((((ks)*4 + kc) ^ (rl & 7)) << 4)]

#define LGKM0() asm volatile("s_waitcnt lgkmcnt(0)" ::: "memory")
#define BAR()   __builtin_amdgcn_s_barrier()

#define MFMA16() do {                                                         \
    __builtin_amdgcn_s_setprio(1);                                            \
    _Pragma("unroll") for (int m = 0; m < 4; ++m) {                           \
      _Pragma("unroll") for (int n = 0; n < 4; ++n)                           \
        acc[m][n] = __builtin_amdgcn_mfma_i32_16x16x64_i8(                    \
            a_[m], b_[n], acc[m][n], 0, 0, 0);                                \
    }                                                                         \
    __builtin_amdgcn_s_setprio(0);                                            \
  } while (0)

    // ---- prologue: stage tile0; certify
    STG_TILE(0);
    asm volatile("s_waitcnt vmcnt(0)" ::: "memory");
    BAR();

    // MODE 1 = steady (stage j+1), 0 = last tile
    auto body = [&](int j, auto modec) {
        constexpr int MODE = decltype(modec)::value;
        // ---- ks0: 8 reads, 16 MFMA
        LD_B(0, 0); LD_B(1, 0); LD_B(2, 0); LD_B(3, 0);
        LD_A(0, 0); LD_A(1, 0); LD_A(2, 0); LD_A(3, 0);
        LGKM0();
        MFMA16();
        // ---- ks1: 8 reads; WAR cert; stage j+1; 16 MFMA; RAW cert
        LD_B(0, 1); LD_B(1, 1); LD_B(2, 1); LD_B(3, 1);
        LD_A(0, 1); LD_A(1, 1); LD_A(2, 1); LD_A(3, 1);
        LGKM0();                  // all my reads of tile j complete
        if constexpr (MODE) {
            BAR();                // buffer free block-wide
            STG_TILE(j + 1);      // HBM/L3 latency hides under MFMA below
        }
        MFMA16();
        if constexpr (MODE) {
            asm volatile("s_waitcnt vmcnt(0)" ::: "memory"); // j+1 landed
            BAR();                // j+1 readable
        }
    };

    for (int j = 0; j < 31; ++j) body(j, IC<1>{});
    body(31, IC<0>{});

    // ---- epilogue: C/D col = lane&15, row = (lane>>4)*4 + i (shape-det.)
    int q = lane >> 4;
#pragma unroll
    for (int n = 0; n < 4; ++n) {
        int col = n0 + wn * 64 + n * 16 + rl;
        float swc = sw[col];
        float bv  = bias[col];
#pragma unroll
        for (int m = 0; m < 4; ++m) {
#pragma unroll
            for (int i = 0; i < 4; ++i) {
                int row = m0 + wm * 64 + m * 16 + q * 4 + i;
                out[(size_t)row * OUT_DIM + col] =
                    (float)acc[m][n][i] * (sx[row] * swc) + bv;
            }
        }
    }
#undef STG_TILE
#undef LD_A
#undef LD_B
#undef LGKM0
#undef BAR
#undef MFMA16
}

// ---------------------------------------------------------------- launch
extern "C" void kernel_launch(void* const* d_in, const int* in_sizes, int n_in,
                              void* d_out, int out_size, void* d_ws, size_t ws_size,
                              hipStream_t stream) {
    const float* x     = (const float*)d_in[0];
    const int*   pw    = (const int*)d_in[1];
    const float* norms = (const float*)d_in[2];
    const float* s1    = (const float*)d_in[3];
    const float* s2    = (const float*)d_in[4];
    const float* cent  = (const float*)d_in[5];
    const float* bias  = (const float*)d_in[6];
    float* out = (float*)d_out;

    size_t offXq = 0;                                   // 64 MB i8 X
    size_t offWq = offXq + (size_t)MROWS * IN_DIM;      // 16 MB i8 W
    size_t offSx = offWq + (size_t)OUT_DIM * IN_DIM;    // 64 KB
    size_t offSw = offSx + (size_t)MROWS * 4;           // 16 KB
    size_t need  = offSw + (size_t)OUT_DIM * 4;
    if (ws_size < need) return;

    signed char* Xq = (signed char*)d_ws + offXq;
    signed char* Wq = (signed char*)d_ws + offWq;
    float*       sx = (float*)((char*)d_ws + offSx);
    float*       sw = (float*)((char*)d_ws + offSw);

    convert_x_i8<<<MROWS, 256, 0, stream>>>(x, Xq, sx);
    decode_quant_w<<<OUT_DIM, 256, 0, stream>>>(pw, norms, s1, s2, cent, Wq, sw);
    gemm_i8<<<(MROWS / 128) * (OUT_DIM / 128), 256, 0, stream>>>(Xq, Wq, sx, sw,
                                                                 bias, out);
}

// Round 21
// 394.978 us; speedup vs baseline: 1.1219x; 1.1219x over previous
//
#include <hip/hip_runtime.h>
#include <hip/hip_bf16.h>

typedef __attribute__((ext_vector_type(4))) int intx4;

#define IN_DIM  4096
#define OUT_DIM 4096
#define MROWS   16384
#define GSIZE   128

template <int N> struct IC { static constexpr int value = N; };

__device__ __forceinline__ int q8(float v, float inv) {
    float q = rintf(v * inv);
    q = fmaxf(-127.f, fminf(127.f, q));
    return (int)q & 0xff;
}

#define GLD16(gsrc, ldst)                                                     \
    __builtin_amdgcn_global_load_lds(                                         \
        (const __attribute__((address_space(1))) unsigned int*)(const void*)(gsrc), \
        (__attribute__((address_space(3))) unsigned int*)(void*)(ldst),       \
        16, 0, 0)

// --------------------------- fused pre-pass: X->i8  (blocks [0,16384)) and
//                             W decode+quant->i8     (blocks [16384,20480))
__global__ void prepass(const float* __restrict__ x,
                        signed char* __restrict__ xq,
                        float* __restrict__ sx,
                        const int* __restrict__ pw,
                        const float* __restrict__ norms,
                        const float* __restrict__ s1,
                        const float* __restrict__ s2,
                        const float* __restrict__ cent,
                        signed char* __restrict__ wq,
                        float* __restrict__ sw) {
    __shared__ float wm[4];
    int tid = threadIdx.x;
    if (blockIdx.x < MROWS) {
        // ---------------- convert X row -> i8 with per-row scale
        int row = blockIdx.x;
        const float4* xr = (const float4*)(x + (size_t)row * IN_DIM);
        float v[16];
        float mx = 0.f;
#pragma unroll
        for (int k = 0; k < 4; ++k) {
            float4 f = xr[tid * 4 + k];
            v[4 * k + 0] = f.x; v[4 * k + 1] = f.y;
            v[4 * k + 2] = f.z; v[4 * k + 3] = f.w;
            mx = fmaxf(mx, fmaxf(fmaxf(fabsf(f.x), fabsf(f.y)),
                                 fmaxf(fabsf(f.z), fabsf(f.w))));
        }
#pragma unroll
        for (int off = 32; off; off >>= 1) mx = fmaxf(mx, __shfl_xor(mx, off));
        if ((tid & 63) == 0) wm[tid >> 6] = mx;
        __syncthreads();
        float bmax = fmaxf(fmaxf(wm[0], wm[1]), fmaxf(wm[2], wm[3]));
        float inv = bmax > 0.f ? 127.f / bmax : 0.f;
        if (tid == 0) sx[row] = bmax > 0.f ? bmax / 127.f : 0.f;
        int p[4];
#pragma unroll
        for (int k = 0; k < 4; ++k)
            p[k] = q8(v[4*k], inv) | (q8(v[4*k+1], inv) << 8) |
                   (q8(v[4*k+2], inv) << 16) | (q8(v[4*k+3], inv) << 24);
        ((int4*)(xq + (size_t)row * IN_DIM))[tid] =
            make_int4(p[0], p[1], p[2], p[3]);
    } else {
        // ---------------- decode + quantize W row -> i8
        int o = blockIdx.x - MROWS;
        int g = tid >> 3;          // group 0..31
        int k = tid & 7;           // elems [k*8, k*8+8) and +64
        const int* pr = pw + ((size_t)o * 32 + g) * GSIZE;
        float nrm = norms[o * 32 + g];
        const float inv = 0.08838834764831845f; // 1/sqrt(128)
        float v0[8], v1[8];
        float mx = 0.f;
#pragma unroll
        for (int i = 0; i < 8; ++i) {
            int idx = k * 8 + i;
            float e0 = cent[pr[idx]]      * nrm * s2[idx];
            float e1 = cent[pr[idx + 64]] * nrm * s2[idx + 64];
#pragma unroll
            for (int it = 0; it < 7; ++it) {
                float a = e0, b = e1;
                e0 = a + b;
                e1 = a - b;
            }
            v0[i] = e0 * inv * s1[idx];
            v1[i] = e1 * inv * s1[idx + 64];
            mx = fmaxf(mx, fmaxf(fabsf(v0[i]), fabsf(v1[i])));
        }
#pragma unroll
        for (int off = 32; off; off >>= 1) mx = fmaxf(mx, __shfl_xor(mx, off));
        if ((tid & 63) == 0) wm[tid >> 6] = mx;
        __syncthreads();
        float bmax = fmaxf(fmaxf(wm[0], wm[1]), fmaxf(wm[2], wm[3]));
        float qinv = bmax > 0.f ? 127.f / bmax : 0.f;
        if (tid == 0) sw[o] = bmax > 0.f ? bmax / 127.f : 0.f;
        int p0 = q8(v0[0],qinv) | (q8(v0[1],qinv)<<8) | (q8(v0[2],qinv)<<16) | (q8(v0[3],qinv)<<24);
        int p1 = q8(v0[4],qinv) | (q8(v0[5],qinv)<<8) | (q8(v0[6],qinv)<<16) | (q8(v0[7],qinv)<<24);
        int p2 = q8(v1[0],qinv) | (q8(v1[1],qinv)<<8) | (q8(v1[2],qinv)<<16) | (q8(v1[3],qinv)<<24);
        int p3 = q8(v1[4],qinv) | (q8(v1[5],qinv)<<8) | (q8(v1[6],qinv)<<16) | (q8(v1[7],qinv)<<24);
        signed char* wr = wq + (size_t)o * IN_DIM + g * GSIZE + k * 8;
        *(int2*)wr        = make_int2(p0, p1);
        *(int2*)(wr + 64) = make_int2(p2, p3);
    }
}

// ---------------------------------------------------------------- GEMM i8
// R19 structure VERBATIM minus s_setprio. Hypothesis: priority-1 MFMA
// waves starved the co-resident block's ds_read issue, defeating the
// cross-block overlap (m190: setprio hurts non-phase-split GEMM). With
// equal priority, one block's DS drain issues during the other's MFMA.
// Block = 128(M) x 256(N), 8 waves (2M x 4N), wave tile 64x64, BK=128,
// single-buffer LDS 48 KiB -> 2 blocks/CU (waves_per_eu=4, 128 regs/wave;
// acc 4x4 = 64 fits). Proven 128B-row / 8-chunk XOR swizzle (0 conflicts).
//
// Per K-tile j (32 tiles):
//   LD ks0 (8 reads); lgkm0; MFMA 16 (ks0)
//   LD ks1 (8 reads); lgkm0; BAR   (all waves' reads of tile j done)
//   STG tile j+1 (6 GLD/thread)
//   MFMA 16 (ks1)
//   vmcnt(0); BAR                  (tile j+1 resident + readable)
__global__ __launch_bounds__(512, 4)
void gemm_i8(const signed char* __restrict__ Xq,
             const signed char* __restrict__ Wq,
             const float* __restrict__ sx,
             const float* __restrict__ sw,
             const float* __restrict__ bias,
             float* __restrict__ out) {
    __shared__ signed char As[128][128];   // 16 KiB
    __shared__ signed char Bs[256][128];   // 32 KiB

    // bijective XCD swizzle (2048 blocks % 8 == 0); consecutive ids share mt
    int id = (blockIdx.x & 7) * 256 + (blockIdx.x >> 3);
    int mt = id >> 4, nt = id & 15;        // 128 M-tiles x 16 N-tiles
    int m0 = mt * 128, n0 = nt * 256;

    int tid  = threadIdx.x;
    int lane = tid & 63;
    int wid  = tid >> 6;
    int wm = wid >> 2, wn = wid & 3;       // wave tile: (wm*64, wn*64)

    // staging: thread covers 16B phys chunk cp0 of rows sr0(+64k)
    int sr0 = tid >> 3;        // 0..63
    int cp0 = tid & 7;         // physical chunk position
    int sg0 = cp0 ^ (sr0 & 7); // global chunk (inverse swizzle)

#define STG_TILE(j) do {                                                      \
    const signed char* _a =                                                   \
        Xq + (size_t)(m0 + sr0) * IN_DIM + (size_t)(j)*128 + sg0*16;          \
    GLD16(_a,                &As[sr0][cp0 * 16]);                             \
    GLD16(_a + 64 * IN_DIM,  &As[sr0 + 64][cp0 * 16]);                        \
    const signed char* _b =                                                   \
        Wq + (size_t)(n0 + sr0) * IN_DIM + (size_t)(j)*128 + sg0*16;          \
    GLD16(_b,                 &Bs[sr0][cp0 * 16]);                            \
    GLD16(_b + 64 * IN_DIM,   &Bs[sr0 + 64][cp0 * 16]);                       \
    GLD16(_b + 128 * IN_DIM,  &Bs[sr0 + 128][cp0 * 16]);                      \
    GLD16(_b + 192 * IN_DIM,  &Bs[sr0 + 192][cp0 * 16]);                      \
  } while (0)

    int rl = lane & 15, kc = lane >> 4;
    intx4 a_[4], b_[4];
    intx4 acc[4][4] = {};

#define LD_A(m, ks)                                                           \
    a_[m] = *(const intx4*)&As[wm*64 + (m)*16 + rl]                           \
        [((((ks)*4 + kc) ^ (rl & 7)) << 4)]
#define LD_B(n, ks)                                                           \
    b_[n] = *(const intx4*)&Bs[wn*64 + (n)*16 + rl]                           \
        [((((ks)*4 + kc) ^ (rl & 7)) << 4)]

#define LGKM0() asm volatile("s_waitcnt lgkmcnt(0)" ::: "memory")
#define BAR()   __builtin_amdgcn_s_barrier()

#define MFMA16() do {                                                         \
    _Pragma("unroll") for (int m = 0; m < 4; ++m) {                           \
      _Pragma("unroll") for (int n = 0; n < 4; ++n)                           \
        acc[m][n] = __builtin_amdgcn_mfma_i32_16x16x64_i8(                    \
            a_[m], b_[n], acc[m][n], 0, 0, 0);                                \
    }                                                                         \
  } while (0)

    // ---- prologue: stage tile0; certify
    STG_TILE(0);
    asm volatile("s_waitcnt vmcnt(0)" ::: "memory");
    BAR();

    // MODE 1 = steady (stage j+1), 0 = last tile
    auto body = [&](int j, auto modec) {
        constexpr int MODE = decltype(modec)::value;
        // ---- ks0: 8 reads, 16 MFMA
        LD_B(0, 0); LD_B(1, 0); LD_B(2, 0); LD_B(3, 0);
        LD_A(0, 0); LD_A(1, 0); LD_A(2, 0); LD_A(3, 0);
        LGKM0();
        MFMA16();
        // ---- ks1: 8 reads; WAR cert; stage j+1; 16 MFMA; RAW cert
        LD_B(0, 1); LD_B(1, 1); LD_B(2, 1); LD_B(3, 1);
        LD_A(0, 1); LD_A(1, 1); LD_A(2, 1); LD_A(3, 1);
        LGKM0();                  // all my reads of tile j complete
        if constexpr (MODE) {
            BAR();                // buffer free block-wide
            STG_TILE(j + 1);      // HBM latency hides under MFMA below
        }
        MFMA16();
        if constexpr (MODE) {
            asm volatile("s_waitcnt vmcnt(0)" ::: "memory"); // j+1 landed
            BAR();                // j+1 readable
        }
    };

    for (int j = 0; j < 31; ++j) body(j, IC<1>{});
    body(31, IC<0>{});

    // ---- epilogue: C/D col = lane&15, row = (lane>>4)*4 + i (shape-det.)
    int q = lane >> 4;
#pragma unroll
    for (int n = 0; n < 4; ++n) {
        int col = n0 + wn * 64 + n * 16 + rl;
        float swc = sw[col];
        float bv  = bias[col];
#pragma unroll
        for (int m = 0; m < 4; ++m) {
#pragma unroll
            for (int i = 0; i < 4; ++i) {
                int row = m0 + wm * 64 + m * 16 + q * 4 + i;
                out[(size_t)row * OUT_DIM + col] =
                    (float)acc[m][n][i] * (sx[row] * swc) + bv;
            }
        }
    }
#undef STG_TILE
#undef LD_A
#undef LD_B
#undef LGKM0
#undef BAR
#undef MFMA16
}

// ---------------------------------------------------------------- launch
extern "C" void kernel_launch(void* const* d_in, const int* in_sizes, int n_in,
                              void* d_out, int out_size, void* d_ws, size_t ws_size,
                              hipStream_t stream) {
    const float* x     = (const float*)d_in[0];
    const int*   pw    = (const int*)d_in[1];
    const float* norms = (const float*)d_in[2];
    const float* s1    = (const float*)d_in[3];
    const float* s2    = (const float*)d_in[4];
    const float* cent  = (const float*)d_in[5];
    const float* bias  = (const float*)d_in[6];
    float* out = (float*)d_out;

    size_t offXq = 0;                                   // 64 MB i8 X
    size_t offWq = offXq + (size_t)MROWS * IN_DIM;      // 16 MB i8 W
    size_t offSx = offWq + (size_t)OUT_DIM * IN_DIM;    // 64 KB
    size_t offSw = offSx + (size_t)MROWS * 4;           // 16 KB
    size_t need  = offSw + (size_t)OUT_DIM * 4;
    if (ws_size < need) return;

    signed char* Xq = (signed char*)d_ws + offXq;
    signed char* Wq = (signed char*)d_ws + offWq;
    float*       sx = (float*)((char*)d_ws + offSx);
    float*       sw = (float*)((char*)d_ws + offSw);

    prepass<<<MROWS + OUT_DIM, 256, 0, stream>>>(x, Xq, sx, pw, norms, s1, s2,
                                                 cent, Wq, sw);
    gemm_i8<<<(MROWS / 128) * (OUT_DIM / 256), 512, 0, stream>>>(Xq, Wq, sx, sw,
                                                                 bias, out);
}